// Round 8
// baseline (393.950 us; speedup 1.0000x reference)
//
#include <hip/hip_runtime.h>
#include <stdint.h>

#define D_MODEL 1024
#define NHEAD   16
#define HEAD_DIM 64
#define BATCH   2
#define SEQ     2048
#define MROWS   (BATCH*SEQ)   // 4096
#define NTILES  (SEQ/64)      // 32 q-tiles per (b,h)

typedef unsigned short bfraw;
typedef __bf16 bf16x8 __attribute__((ext_vector_type(8)));
typedef float  f32x4  __attribute__((ext_vector_type(4)));

__device__ __forceinline__ float bf2f(bfraw u) {
    union { unsigned int i; float f; } w; w.i = ((unsigned int)u) << 16; return w.f;
}
// native RNE f32->bf16 (gfx950 cvt path)
__device__ __forceinline__ bfraw f2bf(float f) {
    union { __bf16 h; bfraw u; } w; w.h = (__bf16)f; return w.u;
}

// ---------------------------------------------------------------------------
// Input conversion: 11 f32 tensors -> contiguous bf16 arena.
// ---------------------------------------------------------------------------
struct CvArgs { const void* src[11]; };
#define CV_TOTAL 16781312ull

__global__ __launch_bounds__(256) void convert_inputs(CvArgs a, bfraw* __restrict__ dst)
{
    const unsigned long long off[12] = {
        0ull, 4194304ull, 8388608ull, 12582912ull,
        13631488ull, 14680064ull, 15728640ull, 16777216ull,
        16778240ull, 16779264ull, 16780288ull, 16781312ull
    };
    size_t i8 = ((size_t)blockIdx.x * 256 + threadIdx.x) * 8;
    if (i8 >= CV_TOTAL) return;
    int t = 0;
#pragma unroll
    for (int s = 1; s < 11; s++) if (i8 >= off[s]) t = s;
    size_t loc = i8 - off[t];
    const float* sp = (const float*)a.src[t] + loc;
    f32x4 v0 = *(const f32x4*)sp;
    f32x4 v1 = *(const f32x4*)(sp + 4);
    uint4 outv;
    bfraw* o = (bfraw*)&outv;
#pragma unroll
    for (int i = 0; i < 4; i++) { o[i] = f2bf(v0[i]); o[4 + i] = f2bf(v1[i]); }
    *(uint4*)(dst + i8) = outv;
}

// ---------------------------------------------------------------------------
// bf16 GEMM, single-barrier double-buffered LDS, register prefetch DISTANCE 2
// (load issued at it is consumed at it+2: ~2 compute phases of latency cover
// vs L2 ~200cyc / HBM ~900cyc). Grid: x = m-block (xcd = m%8), y = n-block.
// ---------------------------------------------------------------------------
template<int TM>
__device__ void gemm_body(const bfraw* __restrict__ X, const bfraw* __restrict__ W,
                          const bfraw* __restrict__ bias, void* __restrict__ Y,
                          int outf32, int vtrans)
{
    constexpr int K = D_MODEL, N = D_MODEL;
    constexpr int NJ  = (TM == 128) ? 4 : 2;
    constexpr int ASZ = 2 * TM * 32;
    constexpr int BSZ = 2 * 128 * 32;
    constexpr int TSZ = 128 * 136;
    constexpr int SMEM_ELEMS =
        (TM == 128) ? ((ASZ + BSZ) > TSZ ? (ASZ + BSZ) : TSZ) : (ASZ + BSZ);
    __shared__ __align__(16) bfraw smem[SMEM_ELEMS];
    bfraw* sA = smem;
    bfraw* sB = smem + ASZ;

    const int tid  = threadIdx.x;
    const int wave = tid >> 6, lane = tid & 63;
    const int col  = lane & 15, quad = lane >> 4;
    const int wm   = (TM == 128) ? (wave & 1) * 64 : 0;
    const int wn   = (TM == 128) ? (wave >> 1) * 64 : wave * 32;
    const int m0   = blockIdx.x * TM, n0 = blockIdx.y * 128;

    f32x4 acc[4][NJ];
    const f32x4 zero = {0.f, 0.f, 0.f, 0.f};
#pragma unroll
    for (int i = 0; i < 4; i++)
#pragma unroll
        for (int j = 0; j < NJ; j++) acc[i][j] = zero;

    const int r0 = tid >> 2;
    const int c8 = (tid & 3) * 8;
    const bfraw* gA0 = X + (size_t)(m0 + r0) * K + c8;
    const bfraw* gA1 = X + (size_t)(m0 + 64 + r0) * K + c8;
    const bfraw* gB0 = W + (size_t)(n0 + r0) * K + c8;
    const bfraw* gB1 = W + (size_t)(n0 + 64 + r0) * K + c8;
    const int la = r0 * 32 + c8;

    uint4 pa0[2], pa1[2], pb0[2], pb1[2];
#pragma unroll
    for (int s = 0; s < 2; s++) {                 // prefetch tiles 0 and 1
        const int k0 = s * 32;
        pa0[s] = *(const uint4*)(gA0 + k0);
        if (TM == 128) pa1[s] = *(const uint4*)(gA1 + k0);
        pb0[s] = *(const uint4*)(gB0 + k0);
        pb1[s] = *(const uint4*)(gB1 + k0);
    }

    for (int it = 0; it < K / 32; it++) {
        const int s = it & 1;
        *(uint4*)(sA + s * TM * 32 + la) = pa0[s];
        if (TM == 128) *(uint4*)(sA + s * TM * 32 + 2048 + la) = pa1[s];
        *(uint4*)(sB + s * 128 * 32 + la) = pb0[s];
        *(uint4*)(sB + s * 128 * 32 + 2048 + la) = pb1[s];
        __syncthreads();
        if (it + 2 < K / 32) {                    // distance-2 prefetch
            const int k0 = (it + 2) * 32;
            pa0[s] = *(const uint4*)(gA0 + k0);
            if (TM == 128) pa1[s] = *(const uint4*)(gA1 + k0);
            pb0[s] = *(const uint4*)(gB0 + k0);
            pb1[s] = *(const uint4*)(gB1 + k0);
        }
        bf16x8 af[4], bfv[NJ];
#pragma unroll
        for (int i = 0; i < 4; i++)
            af[i] = *(const bf16x8*)(sA + s * TM * 32 + (wm + i * 16 + col) * 32 + quad * 8);
#pragma unroll
        for (int j = 0; j < NJ; j++)
            bfv[j] = *(const bf16x8*)(sB + s * 128 * 32 + (wn + j * 16 + col) * 32 + quad * 8);
#pragma unroll
        for (int i = 0; i < 4; i++)
#pragma unroll
            for (int j = 0; j < NJ; j++)
                acc[i][j] = __builtin_amdgcn_mfma_f32_16x16x32_bf16(
                    af[i], bfv[j], acc[i][j], 0, 0, 0);
    }

    if (TM == 128 && vtrans) {
        // V-transpose epilogue via LDS, coalesced global writes
        __syncthreads();
        bfraw* T = smem;
#pragma unroll
        for (int j = 0; j < NJ; j++) {
            int cn = wn + j * 16 + col;
            float bv = bf2f(bias[n0 + cn]);
#pragma unroll
            for (int i = 0; i < 4; i++) {
                int mb = wm + i * 16 + quad * 4;
#pragma unroll
                for (int rg = 0; rg < 4; rg++)
                    T[cn * 136 + mb + rg] = f2bf(acc[i][j][rg] + bv);
            }
        }
        __syncthreads();
        const int nl = tid >> 1, s0 = (tid & 1) * 64;
        const int b = m0 >> 11, sbase = m0 & 2047;
        bfraw* dstp = (bfraw*)Y + ((size_t)(b * 1024 + n0 + nl)) * SEQ + sbase + s0;
        const bfraw* srcp = T + nl * 136 + s0;
#pragma unroll
        for (int u = 0; u < 64; u += 8)
            *(uint4*)(dstp + u) = *(const uint4*)(srcp + u);
        return;
    }

    // standard epilogue: C layout row = quad*4+reg, col = lane&15
#pragma unroll
    for (int j = 0; j < NJ; j++) {
        int cn = n0 + wn + j * 16 + col;
        float bv = bf2f(bias[cn]);
#pragma unroll
        for (int i = 0; i < 4; i++) {
            int rbase = m0 + wm + i * 16 + quad * 4;
#pragma unroll
            for (int rg = 0; rg < 4; rg++) {
                float vv = acc[i][j][rg] + bv;
                size_t idx = (size_t)(rbase + rg) * N + cn;
                if (outf32) ((float*)Y)[idx] = vv;
                else        ((bfraw*)Y)[idx] = f2bf(vv);
            }
        }
    }
}

__global__ __launch_bounds__(256) void qkv_gemm(
    const bfraw* cvQ, const bfraw* cvK, const bfraw* cvV,
    const bfraw* cvW, const bfraw* cvB,
    bfraw* Qs, bfraw* Ks, bfraw* Vt)
{
    const int z = blockIdx.z;
    const bfraw* X = (z == 0) ? cvQ : (z == 1) ? cvK : cvV;
    const bfraw* W = cvW + (size_t)z * D_MODEL * D_MODEL;
    const bfraw* B = cvB + (size_t)z * D_MODEL;
    bfraw*       Y = (z == 0) ? Qs : (z == 1) ? Ks : Vt;
    gemm_body<128>(X, W, B, Y, 0, z == 2);
}

__global__ __launch_bounds__(256) void o_gemm(
    const bfraw* X, const bfraw* W, const bfraw* B, void* Y)
{
    gemm_body<64>(X, W, B, Y, 1, 0);
}

// ---------------------------------------------------------------------------
// Causal flash attention, shuffle-free softmax, distance-2 K/V prefetch.
// P reuses the idle K double-buffer (wave-band ownership; P's lifetime is one
// iteration and tile kt+1's K data is in REGISTERS until its store phase, so
// P never collides with prefetched data).
// Grid: x = bh (xcd = bh%8), y = pair.
// ---------------------------------------------------------------------------
#define NEG_BIG (-1e30f)
#define C_FUSED 0.18033688011112042f   // 0.125 * log2(e)

__device__ __forceinline__ void attn_tile(
    int qt, size_t kqbase, size_t vtbase, int orow_base,
    const bfraw* __restrict__ Qs, const bfraw* __restrict__ Ks,
    const bfraw* __restrict__ Vt, bfraw* __restrict__ Os,
    bfraw* sQ, bfraw (*sK)[64 * 72], bfraw (*sVT)[64 * 72])
{
    const int tid  = threadIdx.x;
    const int wave = tid >> 6, lane = tid & 63;
    const int col  = lane & 15, quad = lane >> 4;
    const int q0   = qt * 64;
    const int r    = tid >> 2;          // wave w covers rows 16w..16w+15
    const int c    = (tid & 3) * 16;

    // wave-private Q staging
    {
        const uint4* src = (const uint4*)(Qs + kqbase + (size_t)(q0 + r) * D_MODEL + c);
        uint4 v0 = src[0], v1 = src[1];
        *(uint4*)(sQ + r * 72 + c)     = v0;
        *(uint4*)(sQ + r * 72 + c + 8) = v1;
    }

    uint4 pk0[2], pk1[2], pv0[2], pv1[2];
#pragma unroll
    for (int s = 0; s < 2; s++) {       // prefetch k-tiles 0,1 (tile 1 always in-bounds)
        const int kn = s * 64;
        const uint4* sk = (const uint4*)(Ks + kqbase + (size_t)(kn + r) * D_MODEL + c);
        pk0[s] = sk[0]; pk1[s] = sk[1];
        const uint4* sv = (const uint4*)(Vt + vtbase + (size_t)r * SEQ + kn + c);
        pv0[s] = sv[0]; pv1[s] = sv[1];
    }

    f32x4 o_acc[4], l_acc;
    const f32x4 zero = {0.f, 0.f, 0.f, 0.f};
#pragma unroll
    for (int d = 0; d < 4; d++) o_acc[d] = zero;
    l_acc = zero;

    bf16x8 onesv;
#pragma unroll
    for (int i = 0; i < 8; i++) onesv[i] = (__bf16)1.0f;

    __syncthreads();   // entry: prior tile's LDS readers done before first store

    for (int kt = 0; kt <= qt; kt++) {
        const int k0 = kt * 64;
        const int s = kt & 1;
        *(uint4*)(sK[s]  + r * 72 + c)     = pk0[s];
        *(uint4*)(sK[s]  + r * 72 + c + 8) = pk1[s];
        *(uint4*)(sVT[s] + r * 72 + c)     = pv0[s];
        *(uint4*)(sVT[s] + r * 72 + c + 8) = pv1[s];
        __syncthreads();
        if (kt + 2 <= qt) {             // distance-2 prefetch
            const int kn = (kt + 2) * 64;
            const uint4* sk = (const uint4*)(Ks + kqbase + (size_t)(kn + r) * D_MODEL + c);
            pk0[s] = sk[0]; pk1[s] = sk[1];
            const uint4* sv = (const uint4*)(Vt + vtbase + (size_t)r * SEQ + kn + c);
            pv0[s] = sv[0]; pv1[s] = sv[1];
        }

        // S = Q K^T
        f32x4 s_acc[4];
#pragma unroll
        for (int j = 0; j < 4; j++) s_acc[j] = zero;
#pragma unroll
        for (int kk = 0; kk < 2; kk++) {
            bf16x8 a = *(const bf16x8*)(sQ + (wave * 16 + col) * 72 + kk * 32 + quad * 8);
#pragma unroll
            for (int j = 0; j < 4; j++) {
                bf16x8 bb = *(const bf16x8*)(sK[s] + (j * 16 + col) * 72 + kk * 32 + quad * 8);
                s_acc[j] = __builtin_amdgcn_mfma_f32_16x16x32_bf16(a, bb, s_acc[j], 0, 0, 0);
            }
        }

        // P = exp2(s*C), causal mask on diag tile; into idle K buffer
        bfraw* sP = sK[s ^ 1];
        const bool diag = (kt == qt);
#pragma unroll
        for (int j = 0; j < 4; j++) {
#pragma unroll
            for (int rg = 0; rg < 4; rg++) {
                float x = s_acc[j][rg] * C_FUSED;
                if (diag) {
                    int kg = k0 + j * 16 + col;
                    int qg = q0 + wave * 16 + quad * 4 + rg;
                    if (kg > qg) x = NEG_BIG;
                }
                float p = __builtin_amdgcn_exp2f(x);
                sP[(wave * 16 + quad * 4 + rg) * 72 + j * 16 + col] = f2bf(p);
            }
        }

        // O += P @ V ; l += P @ ones
#pragma unroll
        for (int kk = 0; kk < 2; kk++) {
            bf16x8 a = *(const bf16x8*)(sP + (wave * 16 + col) * 72 + kk * 32 + quad * 8);
#pragma unroll
            for (int d = 0; d < 4; d++) {
                bf16x8 bb = *(const bf16x8*)(sVT[s] + (d * 16 + col) * 72 + kk * 32 + quad * 8);
                o_acc[d] = __builtin_amdgcn_mfma_f32_16x16x32_bf16(a, bb, o_acc[d], 0, 0, 0);
            }
            l_acc = __builtin_amdgcn_mfma_f32_16x16x32_bf16(a, onesv, l_acc, 0, 0, 0);
        }
    }

    // epilogue
#pragma unroll
    for (int rg = 0; rg < 4; rg++) {
        float inv = 1.0f / l_acc[rg];
        int qg = q0 + wave * 16 + quad * 4 + rg;
        size_t rowoff = (size_t)(orow_base + qg) * D_MODEL;
#pragma unroll
        for (int d = 0; d < 4; d++)
            Os[rowoff + d * 16 + col] = f2bf(o_acc[d][rg] * inv);
    }
}

__global__ __launch_bounds__(256) void flash_attn(
    const bfraw* __restrict__ Qs, const bfraw* __restrict__ Ks,
    const bfraw* __restrict__ Vt, bfraw* __restrict__ Os)
{
    __shared__ bfraw sQ [64 * 72];
    __shared__ bfraw sK [2][64 * 72];
    __shared__ bfraw sVT[2][64 * 72];

    const int bh   = blockIdx.x;        // fastest -> xcd = bh%8
    const int pair = blockIdx.y;        // 0..15
    const int b    = bh >> 4, h = bh & 15;
    const size_t kqbase = (size_t)(b * SEQ) * D_MODEL + h * HEAD_DIM;
    const size_t vtbase = (size_t)(b * 1024 + h * HEAD_DIM) * SEQ;
    const int orow = b * SEQ;

    // balanced causal pairing: (pair+1) + (32-pair) = 33 k-tiles per block
    attn_tile(pair,              kqbase, vtbase, orow, Qs, Ks, Vt,
              Os + h * HEAD_DIM, sQ, sK, sVT);
    attn_tile(NTILES - 1 - pair, kqbase, vtbase, orow, Qs, Ks, Vt,
              Os + h * HEAD_DIM, sQ, sK, sVT);
}

// ---------------------------------------------------------------------------
extern "C" void kernel_launch(void* const* d_in, const int* in_sizes, int n_in,
                              void* d_out, int out_size, void* d_ws, size_t ws_size,
                              hipStream_t stream) {
    bfraw* arena = (bfraw*)d_ws;
    bfraw* cvQ = arena;
    bfraw* cvK = arena + 4194304;
    bfraw* cvV = arena + 8388608;
    bfraw* cvW = arena + 12582912;
    bfraw* cvB = arena + 16777216;
    bfraw* Qs  = (bfraw*)((char*)d_ws + 33562624);
    bfraw* Ks  = Qs + (size_t)MROWS * D_MODEL;
    bfraw* Vt  = Ks + (size_t)MROWS * D_MODEL;
    bfraw* As  = cvQ;                         // alias: cv inputs dead by then

    CvArgs cva;
    cva.src[0] = d_in[0];  cva.src[1] = d_in[1];  cva.src[2] = d_in[2];
    cva.src[3] = d_in[4];  cva.src[4] = d_in[6];  cva.src[5] = d_in[8];
    cva.src[6] = d_in[10];
    cva.src[7] = d_in[5];  cva.src[8] = d_in[7];  cva.src[9] = d_in[9];
    cva.src[10] = d_in[11];

    dim3 blk(256);
    convert_inputs<<<dim3((unsigned)(CV_TOTAL / 8 / 256)), blk, 0, stream>>>(cva, arena);
    qkv_gemm<<<dim3(MROWS / 128, D_MODEL / 128, 3), blk, 0, stream>>>(
        cvQ, cvK, cvV, cvW, cvB, Qs, Ks, Vt);
    flash_attn<<<dim3(BATCH * NHEAD, NTILES / 2), blk, 0, stream>>>(Qs, Ks, Vt, As);
    o_gemm<<<dim3(MROWS / 64, D_MODEL / 128), blk, 0, stream>>>(
        As, cvW + 3 * (size_t)D_MODEL * D_MODEL, cvB + 3 * D_MODEL, d_out);
}

// Round 9
// 227.727 us; speedup vs baseline: 1.7299x; 1.7299x over previous
//
#include <hip/hip_runtime.h>
#include <stdint.h>

#define D_MODEL 1024
#define NHEAD   16
#define HEAD_DIM 64
#define BATCH   2
#define SEQ     2048
#define MROWS   (BATCH*SEQ)   // 4096
#define NTILES  (SEQ/64)      // 32 q-tiles per (b,h)

typedef unsigned short bfraw;
typedef __bf16 bf16x8 __attribute__((ext_vector_type(8)));
typedef float  f32x4  __attribute__((ext_vector_type(4)));

__device__ __forceinline__ float bf2f(bfraw u) {
    union { unsigned int i; float f; } w; w.i = ((unsigned int)u) << 16; return w.f;
}
// native RNE f32->bf16 (gfx950 cvt path)
__device__ __forceinline__ bfraw f2bf(float f) {
    union { __bf16 h; bfraw u; } w; w.h = (__bf16)f; return w.u;
}

// ---------------------------------------------------------------------------
// Input conversion: 11 f32 tensors -> contiguous bf16 arena.
// ---------------------------------------------------------------------------
struct CvArgs { const void* src[11]; };
#define CV_TOTAL 16781312ull

__global__ __launch_bounds__(256) void convert_inputs(CvArgs a, bfraw* __restrict__ dst)
{
    const unsigned long long off[12] = {
        0ull, 4194304ull, 8388608ull, 12582912ull,
        13631488ull, 14680064ull, 15728640ull, 16777216ull,
        16778240ull, 16779264ull, 16780288ull, 16781312ull
    };
    size_t i8 = ((size_t)blockIdx.x * 256 + threadIdx.x) * 8;
    if (i8 >= CV_TOTAL) return;
    int t = 0;
#pragma unroll
    for (int s = 1; s < 11; s++) if (i8 >= off[s]) t = s;
    size_t loc = i8 - off[t];
    const float* sp = (const float*)a.src[t] + loc;
    f32x4 v0 = *(const f32x4*)sp;
    f32x4 v1 = *(const f32x4*)(sp + 4);
    uint4 outv;
    bfraw* o = (bfraw*)&outv;
#pragma unroll
    for (int i = 0; i < 4; i++) { o[i] = f2bf(v0[i]); o[4 + i] = f2bf(v1[i]); }
    *(uint4*)(dst + i8) = outv;
}

// ---------------------------------------------------------------------------
// bf16 GEMM, double-buffered LDS, TRUE distance-2 register prefetch:
// K-loop unrolled x2 with two SCALAR prefetch sets (compile-time indices only
// -- dynamically-indexed locals demote to scratch: round-8 regression,
// WRITE_SIZE 24->256MB). One barrier per BK=32 iteration.
// Grid: x = m-block (xcd = m%8), y = n-block.
// ---------------------------------------------------------------------------
template<int TM>
__device__ void gemm_body(const bfraw* __restrict__ X, const bfraw* __restrict__ W,
                          const bfraw* __restrict__ bias, void* __restrict__ Y,
                          int outf32, int vtrans)
{
    constexpr int K = D_MODEL, N = D_MODEL;
    constexpr int NJ  = (TM == 128) ? 4 : 2;
    constexpr int ASZ = 2 * TM * 32;
    constexpr int BSZ = 2 * 128 * 32;
    constexpr int TSZ = 128 * 136;
    constexpr int SMEM_ELEMS =
        (TM == 128) ? ((ASZ + BSZ) > TSZ ? (ASZ + BSZ) : TSZ) : (ASZ + BSZ);
    __shared__ __align__(16) bfraw smem[SMEM_ELEMS];
    bfraw* sA = smem;
    bfraw* sB = smem + ASZ;

    const int tid  = threadIdx.x;
    const int wave = tid >> 6, lane = tid & 63;
    const int col  = lane & 15, quad = lane >> 4;
    const int wm   = (TM == 128) ? (wave & 1) * 64 : 0;
    const int wn   = (TM == 128) ? (wave >> 1) * 64 : wave * 32;
    const int m0   = blockIdx.x * TM, n0 = blockIdx.y * 128;

    f32x4 acc[4][NJ];
    const f32x4 zero = {0.f, 0.f, 0.f, 0.f};
#pragma unroll
    for (int i = 0; i < 4; i++)
#pragma unroll
        for (int j = 0; j < NJ; j++) acc[i][j] = zero;

    const int r0 = tid >> 2;
    const int c8 = (tid & 3) * 8;
    const bfraw* gA0 = X + (size_t)(m0 + r0) * K + c8;
    const bfraw* gA1 = X + (size_t)(m0 + 64 + r0) * K + c8;
    const bfraw* gB0 = W + (size_t)(n0 + r0) * K + c8;
    const bfraw* gB1 = W + (size_t)(n0 + 64 + r0) * K + c8;
    const int la = r0 * 32 + c8;

    // two scalar prefetch sets: e = even iterations (buf0), o = odd (buf1)
    uint4 a0e, a1e, b0e, b1e, a0o, a1o, b0o, b1o;
    a0e = *(const uint4*)gA0;
    if (TM == 128) a1e = *(const uint4*)gA1;
    b0e = *(const uint4*)gB0;
    b1e = *(const uint4*)gB1;
    a0o = *(const uint4*)(gA0 + 32);
    if (TM == 128) a1o = *(const uint4*)(gA1 + 32);
    b0o = *(const uint4*)(gB0 + 32);
    b1o = *(const uint4*)(gB1 + 32);

    auto compute = [&](const bfraw* bA, const bfraw* bB) {
        bf16x8 af[4], bfv[NJ];
#pragma unroll
        for (int i = 0; i < 4; i++)
            af[i] = *(const bf16x8*)(bA + (wm + i * 16 + col) * 32 + quad * 8);
#pragma unroll
        for (int j = 0; j < NJ; j++)
            bfv[j] = *(const bf16x8*)(bB + (wn + j * 16 + col) * 32 + quad * 8);
#pragma unroll
        for (int i = 0; i < 4; i++)
#pragma unroll
            for (int j = 0; j < NJ; j++)
                acc[i][j] = __builtin_amdgcn_mfma_f32_16x16x32_bf16(
                    af[i], bfv[j], acc[i][j], 0, 0, 0);
    };

    for (int it = 0; it < K / 32; it += 2) {
        // even phase -> buffer 0
        *(uint4*)(sA + la) = a0e;
        if (TM == 128) *(uint4*)(sA + 2048 + la) = a1e;
        *(uint4*)(sB + la) = b0e;
        *(uint4*)(sB + 2048 + la) = b1e;
        __syncthreads();
        if (it + 2 < K / 32) {              // distance-2: consumed at it+2
            const int k0 = (it + 2) * 32;
            a0e = *(const uint4*)(gA0 + k0);
            if (TM == 128) a1e = *(const uint4*)(gA1 + k0);
            b0e = *(const uint4*)(gB0 + k0);
            b1e = *(const uint4*)(gB1 + k0);
        }
        compute(sA, sB);

        // odd phase -> buffer 1
        *(uint4*)(sA + TM * 32 + la) = a0o;
        if (TM == 128) *(uint4*)(sA + TM * 32 + 2048 + la) = a1o;
        *(uint4*)(sB + 128 * 32 + la) = b0o;
        *(uint4*)(sB + 128 * 32 + 2048 + la) = b1o;
        __syncthreads();
        if (it + 3 < K / 32) {
            const int k0 = (it + 3) * 32;
            a0o = *(const uint4*)(gA0 + k0);
            if (TM == 128) a1o = *(const uint4*)(gA1 + k0);
            b0o = *(const uint4*)(gB0 + k0);
            b1o = *(const uint4*)(gB1 + k0);
        }
        compute(sA + TM * 32, sB + 128 * 32);
    }

    if (TM == 128 && vtrans) {
        // V-transpose epilogue via LDS, coalesced global writes
        __syncthreads();
        bfraw* T = smem;
#pragma unroll
        for (int j = 0; j < NJ; j++) {
            int cn = wn + j * 16 + col;
            float bv = bf2f(bias[n0 + cn]);
#pragma unroll
            for (int i = 0; i < 4; i++) {
                int mb = wm + i * 16 + quad * 4;
#pragma unroll
                for (int rg = 0; rg < 4; rg++)
                    T[cn * 136 + mb + rg] = f2bf(acc[i][j][rg] + bv);
            }
        }
        __syncthreads();
        const int nl = tid >> 1, s0 = (tid & 1) * 64;
        const int b = m0 >> 11, sbase = m0 & 2047;
        bfraw* dstp = (bfraw*)Y + ((size_t)(b * 1024 + n0 + nl)) * SEQ + sbase + s0;
        const bfraw* srcp = T + nl * 136 + s0;
#pragma unroll
        for (int u = 0; u < 64; u += 8)
            *(uint4*)(dstp + u) = *(const uint4*)(srcp + u);
        return;
    }

    // standard epilogue: C layout row = quad*4+reg, col = lane&15
#pragma unroll
    for (int j = 0; j < NJ; j++) {
        int cn = n0 + wn + j * 16 + col;
        float bv = bf2f(bias[cn]);
#pragma unroll
        for (int i = 0; i < 4; i++) {
            int rbase = m0 + wm + i * 16 + quad * 4;
#pragma unroll
            for (int rg = 0; rg < 4; rg++) {
                float vv = acc[i][j][rg] + bv;
                size_t idx = (size_t)(rbase + rg) * N + cn;
                if (outf32) ((float*)Y)[idx] = vv;
                else        ((bfraw*)Y)[idx] = f2bf(vv);
            }
        }
    }
}

__global__ __launch_bounds__(256) void qkv_gemm(
    const bfraw* cvQ, const bfraw* cvK, const bfraw* cvV,
    const bfraw* cvW, const bfraw* cvB,
    bfraw* Qs, bfraw* Ks, bfraw* Vt)
{
    const int z = blockIdx.z;
    const bfraw* X = (z == 0) ? cvQ : (z == 1) ? cvK : cvV;
    const bfraw* W = cvW + (size_t)z * D_MODEL * D_MODEL;
    const bfraw* B = cvB + (size_t)z * D_MODEL;
    bfraw*       Y = (z == 0) ? Qs : (z == 1) ? Ks : Vt;
    gemm_body<128>(X, W, B, Y, 0, z == 2);
}

__global__ __launch_bounds__(256) void o_gemm(
    const bfraw* X, const bfraw* W, const bfraw* B, void* Y)
{
    gemm_body<64>(X, W, B, Y, 1, 0);
}

// ---------------------------------------------------------------------------
// Causal flash attention (round-7 known-good structure: scalar distance-1
// prefetch). Shuffle-free softmax; l via MFMA ones-column; P reuses the idle
// K double-buffer (wave-band ownership). Grid: x = bh (xcd = bh%8), y = pair.
// ---------------------------------------------------------------------------
#define NEG_BIG (-1e30f)
#define C_FUSED 0.18033688011112042f   // 0.125 * log2(e)

__device__ __forceinline__ void attn_tile(
    int qt, size_t kqbase, size_t vtbase, int orow_base,
    const bfraw* __restrict__ Qs, const bfraw* __restrict__ Ks,
    const bfraw* __restrict__ Vt, bfraw* __restrict__ Os,
    bfraw* sQ, bfraw (*sK)[64 * 72], bfraw (*sVT)[64 * 72])
{
    const int tid  = threadIdx.x;
    const int wave = tid >> 6, lane = tid & 63;
    const int col  = lane & 15, quad = lane >> 4;
    const int q0   = qt * 64;
    const int r    = tid >> 2;          // wave w covers rows 16w..16w+15
    const int c    = (tid & 3) * 16;

    // wave-private Q staging
    {
        const uint4* src = (const uint4*)(Qs + kqbase + (size_t)(q0 + r) * D_MODEL + c);
        uint4 v0 = src[0], v1 = src[1];
        *(uint4*)(sQ + r * 72 + c)     = v0;
        *(uint4*)(sQ + r * 72 + c + 8) = v1;
    }

    uint4 pk0, pk1, pv0, pv1;
    {   // prefetch k-tile 0
        const uint4* sk = (const uint4*)(Ks + kqbase + (size_t)r * D_MODEL + c);
        pk0 = sk[0]; pk1 = sk[1];
        const uint4* sv = (const uint4*)(Vt + vtbase + (size_t)r * SEQ + c);
        pv0 = sv[0]; pv1 = sv[1];
    }

    f32x4 o_acc[4], l_acc;
    const f32x4 zero = {0.f, 0.f, 0.f, 0.f};
#pragma unroll
    for (int d = 0; d < 4; d++) o_acc[d] = zero;
    l_acc = zero;

    bf16x8 onesv;
#pragma unroll
    for (int i = 0; i < 8; i++) onesv[i] = (__bf16)1.0f;

    __syncthreads();   // entry: prior tile's LDS readers done before first store

    for (int kt = 0; kt <= qt; kt++) {
        const int k0 = kt * 64;
        const int buf = kt & 1;
        *(uint4*)(sK[buf]  + r * 72 + c)     = pk0;
        *(uint4*)(sK[buf]  + r * 72 + c + 8) = pk1;
        *(uint4*)(sVT[buf] + r * 72 + c)     = pv0;
        *(uint4*)(sVT[buf] + r * 72 + c + 8) = pv1;
        __syncthreads();
        if (kt < qt) {
            const int kn = (kt + 1) * 64;
            const uint4* sk = (const uint4*)(Ks + kqbase + (size_t)(kn + r) * D_MODEL + c);
            pk0 = sk[0]; pk1 = sk[1];
            const uint4* sv = (const uint4*)(Vt + vtbase + (size_t)r * SEQ + kn + c);
            pv0 = sv[0]; pv1 = sv[1];
        }

        // S = Q K^T
        f32x4 s_acc[4];
#pragma unroll
        for (int j = 0; j < 4; j++) s_acc[j] = zero;
#pragma unroll
        for (int kk = 0; kk < 2; kk++) {
            bf16x8 a = *(const bf16x8*)(sQ + (wave * 16 + col) * 72 + kk * 32 + quad * 8);
#pragma unroll
            for (int j = 0; j < 4; j++) {
                bf16x8 bb = *(const bf16x8*)(sK[buf] + (j * 16 + col) * 72 + kk * 32 + quad * 8);
                s_acc[j] = __builtin_amdgcn_mfma_f32_16x16x32_bf16(a, bb, s_acc[j], 0, 0, 0);
            }
        }

        // P = exp2(s*C), causal mask on diag tile; into idle K buffer
        bfraw* sP = sK[buf ^ 1];
        const bool diag = (kt == qt);
#pragma unroll
        for (int j = 0; j < 4; j++) {
#pragma unroll
            for (int rg = 0; rg < 4; rg++) {
                float x = s_acc[j][rg] * C_FUSED;
                if (diag) {
                    int kg = k0 + j * 16 + col;
                    int qg = q0 + wave * 16 + quad * 4 + rg;
                    if (kg > qg) x = NEG_BIG;
                }
                float p = __builtin_amdgcn_exp2f(x);
                sP[(wave * 16 + quad * 4 + rg) * 72 + j * 16 + col] = f2bf(p);
            }
        }

        // O += P @ V ; l += P @ ones
#pragma unroll
        for (int kk = 0; kk < 2; kk++) {
            bf16x8 a = *(const bf16x8*)(sP + (wave * 16 + col) * 72 + kk * 32 + quad * 8);
#pragma unroll
            for (int d = 0; d < 4; d++) {
                bf16x8 bb = *(const bf16x8*)(sVT[buf] + (d * 16 + col) * 72 + kk * 32 + quad * 8);
                o_acc[d] = __builtin_amdgcn_mfma_f32_16x16x32_bf16(a, bb, o_acc[d], 0, 0, 0);
            }
            l_acc = __builtin_amdgcn_mfma_f32_16x16x32_bf16(a, onesv, l_acc, 0, 0, 0);
        }
    }

    // epilogue
#pragma unroll
    for (int rg = 0; rg < 4; rg++) {
        float inv = 1.0f / l_acc[rg];
        int qg = q0 + wave * 16 + quad * 4 + rg;
        size_t rowoff = (size_t)(orow_base + qg) * D_MODEL;
#pragma unroll
        for (int d = 0; d < 4; d++)
            Os[rowoff + d * 16 + col] = f2bf(o_acc[d][rg] * inv);
    }
}

__global__ __launch_bounds__(256) void flash_attn(
    const bfraw* __restrict__ Qs, const bfraw* __restrict__ Ks,
    const bfraw* __restrict__ Vt, bfraw* __restrict__ Os)
{
    __shared__ bfraw sQ [64 * 72];
    __shared__ bfraw sK [2][64 * 72];
    __shared__ bfraw sVT[2][64 * 72];

    const int bh   = blockIdx.x;        // fastest -> xcd = bh%8
    const int pair = blockIdx.y;        // 0..15
    const int b    = bh >> 4, h = bh & 15;
    const size_t kqbase = (size_t)(b * SEQ) * D_MODEL + h * HEAD_DIM;
    const size_t vtbase = (size_t)(b * 1024 + h * HEAD_DIM) * SEQ;
    const int orow = b * SEQ;

    // balanced causal pairing: (pair+1) + (32-pair) = 33 k-tiles per block
    attn_tile(pair,              kqbase, vtbase, orow, Qs, Ks, Vt,
              Os + h * HEAD_DIM, sQ, sK, sVT);
    attn_tile(NTILES - 1 - pair, kqbase, vtbase, orow, Qs, Ks, Vt,
              Os + h * HEAD_DIM, sQ, sK, sVT);
}

// ---------------------------------------------------------------------------
extern "C" void kernel_launch(void* const* d_in, const int* in_sizes, int n_in,
                              void* d_out, int out_size, void* d_ws, size_t ws_size,
                              hipStream_t stream) {
    bfraw* arena = (bfraw*)d_ws;
    bfraw* cvQ = arena;
    bfraw* cvK = arena + 4194304;
    bfraw* cvV = arena + 8388608;
    bfraw* cvW = arena + 12582912;
    bfraw* cvB = arena + 16777216;
    bfraw* Qs  = (bfraw*)((char*)d_ws + 33562624);
    bfraw* Ks  = Qs + (size_t)MROWS * D_MODEL;
    bfraw* Vt  = Ks + (size_t)MROWS * D_MODEL;
    bfraw* As  = cvQ;                         // alias: cv inputs dead by then

    CvArgs cva;
    cva.src[0] = d_in[0];  cva.src[1] = d_in[1];  cva.src[2] = d_in[2];
    cva.src[3] = d_in[4];  cva.src[4] = d_in[6];  cva.src[5] = d_in[8];
    cva.src[6] = d_in[10];
    cva.src[7] = d_in[5];  cva.src[8] = d_in[7];  cva.src[9] = d_in[9];
    cva.src[10] = d_in[11];

    dim3 blk(256);
    convert_inputs<<<dim3((unsigned)(CV_TOTAL / 8 / 256)), blk, 0, stream>>>(cva, arena);
    qkv_gemm<<<dim3(MROWS / 128, D_MODEL / 128, 3), blk, 0, stream>>>(
        cvQ, cvK, cvV, cvW, cvB, Qs, Ks, Vt);
    flash_attn<<<dim3(BATCH * NHEAD, NTILES / 2), blk, 0, stream>>>(Qs, Ks, Vt, As);
    o_gemm<<<dim3(MROWS / 64, D_MODEL / 128), blk, 0, stream>>>(
        As, cvW + 3 * (size_t)D_MODEL * D_MODEL, cvB + 3 * D_MODEL, d_out);
}